// Round 6
// baseline (26320.300 us; speedup 1.0000x reference)
//
#include <hip/hip_runtime.h>
#include <hip/hip_bf16.h>
#include <stdint.h>

// ESN: out[t] = tanh(U[t] + W_res @ s_{t-1}), T=16384 sequential steps.
// Kernel 1: U = X@W_in^T into d_out in place.
// Kernel 2: 8 worker blocks x 1024 threads claimed on ONE XCD via XCC_ID
// pigeonhole (proven). Transport = R0's PROVEN per-slot L2-atomic poll
// (HW fact R4: only sc0 atomic RMWs observe remote plain stores; plain/sc0
// loads are L1-stale forever). 4B packet {24-bit value | 8-bit tag}.
// R6 deltas vs R5 (25.2ms) / R0 (24.7ms):
//   (a) REVERT dual-copy bank skew (R5: conflicts +13%, pure overhead --
//       re-hashing iid-random columns can't reduce collisions).
//   (b) Bank-aware per-lane slot reorder: one-time statically-unrolled
//       selection sort of each lane's (col,val) by key (col - tid) & 31
//       -> round-k banks ~ tid + k*delta, near-uniform lane->bank spread
//       per gather round (2-way max = free). Pad slots col = tid
//       (distinct) instead of 0 (was a 32-way pileup in tail rounds).
//   (c) Poll-ahead pipeline: ISSUE next step's slot atomic (no waitcnt)
//       right after the barrier; it flies during the gather; WAIT +
//       tag-check at next iteration top (value-tied "+v" waitcnt asm +
//       sched_barrier(0) per rule #18). Laggard block (= critical path)
//       always hits first-try -> hides the ~300cy round trip. Stale
//       pre-reads fall into the unchanged retry loop.
//   u_next is issued AFTER the wait so its latency hides under gather.

constexpr int T_N = 16384;
constexpr int R_N = 1024;
constexpr int I_N = 128;

// ---------------------------------------------------------------- kernel 1
constexpr int BT = 64, BR = 64;

__global__ __launch_bounds__(256) void gemm_u_kernel(
    const float* __restrict__ X, const float* __restrict__ Win,
    float* __restrict__ U)
{
    __shared__ float XS[BT][68];
    __shared__ float WS[BR][68];
    const int tid = threadIdx.x;
    const int ty = tid >> 4, tx = tid & 15;
    const int t0 = blockIdx.x * BT;
    const int r0 = blockIdx.y * BR;
    float acc[4][4] = {};

    for (int k0 = 0; k0 < I_N; k0 += 64) {
        for (int idx = tid; idx < BT * 16; idx += 256) {
            int row = idx >> 4, c4 = (idx & 15) << 2;
            *reinterpret_cast<float4*>(&XS[row][c4]) =
                *reinterpret_cast<const float4*>(&X[(size_t)(t0 + row) * I_N + k0 + c4]);
        }
        for (int idx = tid; idx < BR * 16; idx += 256) {
            int row = idx >> 4, c4 = (idx & 15) << 2;
            *reinterpret_cast<float4*>(&WS[row][c4]) =
                *reinterpret_cast<const float4*>(&Win[(size_t)(r0 + row) * I_N + k0 + c4]);
        }
        __syncthreads();
#pragma unroll
        for (int k = 0; k < 64; k += 4) {
            float4 a[4], b[4];
#pragma unroll
            for (int i = 0; i < 4; ++i)
                a[i] = *reinterpret_cast<const float4*>(&XS[ty + 16 * i][k]);
#pragma unroll
            for (int jj = 0; jj < 4; ++jj)
                b[jj] = *reinterpret_cast<const float4*>(&WS[tx + 16 * jj][k]);
#pragma unroll
            for (int i = 0; i < 4; ++i)
#pragma unroll
                for (int jj = 0; jj < 4; ++jj)
                    acc[i][jj] += a[i].x * b[jj].x + a[i].y * b[jj].y +
                                  a[i].z * b[jj].z + a[i].w * b[jj].w;
        }
        __syncthreads();
    }
#pragma unroll
    for (int i = 0; i < 4; ++i)
#pragma unroll
        for (int jj = 0; jj < 4; ++jj)
            U[(size_t)(t0 + ty + 16 * i) * R_N + (r0 + tx + 16 * jj)] = acc[i][jj];
}

// ---------------------------------------------------------------- kernel 2
constexpr int GBLK    = 8;             // worker blocks (one XCD)
constexpr int NLAUNCH = 64;            // pigeonhole: some XCD collects 8
constexpr int B2      = 1024;          // 1 poll slot per thread
constexpr int RPB     = R_N / GBLK;    // 128 rows per block
constexpr int TPR     = 8;             // threads per row
constexpr int KMAX    = 96;            // nnz/row cap (validated r1..r5)
constexpr int NSL     = KMAX / TPR;    // 12 register slots per thread
constexpr int PCAP    = 1 << 20;       // anti-hang cap

__device__ __forceinline__ float fast_tanh(float x) {
    float ax = fabsf(x);
    float e  = __expf(-2.0f * ax);
    float y  = (1.0f - e) / (1.0f + e);
    return copysignf(y, x);
}

// SE-scope atomic add 0 with return: executes at the XCD L2 -- the ONLY
// load primitive proven coherent with remote plain stores (R0/R4).
__device__ __forceinline__ uint32_t l2_atomic_read(uint32_t* addr) {
    uint32_t old;
    asm volatile("global_atomic_add %0, %1, %2, off sc0\n\t"
                 "s_waitcnt vmcnt(0)"
                 : "=v"(old) : "v"(addr), "v"(0u) : "memory");
    return old;
}

// issue-only variant: result register valid ONLY after a later vmcnt wait
__device__ __forceinline__ void l2_atomic_read_issue(uint32_t* addr, uint32_t& dst) {
    asm volatile("global_atomic_add %0, %1, %2, off sc0"
                 : "=v"(dst) : "v"(addr), "v"(0u) : "memory");
}

// plain 4B store: dirty line in the shared XCD L2 (visible to sc0 RMWs)
__device__ __forceinline__ void l2_store_u32(uint32_t* addr, uint32_t v) {
    asm volatile("global_store_dword %0, %1, off"
                 :: "v"(addr), "v"(v) : "memory");
}

__global__ __launch_bounds__(1024) void esn_scan_kernel(
    const float* __restrict__ Wres, const float* __restrict__ state0,
    float* out, uint32_t* hdr, uint32_t* slots)
{
    __shared__ int   s_role;
    __shared__ float sbuf[2][R_N];        // 8 KB ping-pong state
    __shared__ uint2 ell[RPB][KMAX];      // 96 KB (col, val-bits)
    __shared__ int   cnt[RPB];
    __shared__ int   rowmap[RPB];         // nnz-ascending row permutation
    __shared__ int   hist[KMAX + 1];      // counting-sort scratch

    const int tid = threadIdx.x;

    // ---- claim: first XCD to collect 8 blocks wins (proven mechanism)
    if (tid == 0) {
        uint32_t xcd;
        asm volatile("s_getreg_b32 %0, hwreg(HW_REG_XCC_ID)" : "=s"(xcd));
        xcd &= 7u;
        uint32_t rank = __hip_atomic_fetch_add(&hdr[xcd], 1u,
                            __ATOMIC_RELAXED, __HIP_MEMORY_SCOPE_AGENT);
        int role = -1;
        if (rank < (uint32_t)GBLK) {
            if (rank == (uint32_t)(GBLK - 1)) {
                uint32_t expected = 0u;
                __hip_atomic_compare_exchange_strong(&hdr[8], &expected, xcd + 1u,
                    __ATOMIC_RELAXED, __ATOMIC_RELAXED, __HIP_MEMORY_SCOPE_AGENT);
            }
            uint32_t win = 0; int sp = 0;
            do {
                win = __hip_atomic_load(&hdr[8], __ATOMIC_RELAXED,
                                        __HIP_MEMORY_SCOPE_AGENT);
            } while (win == 0u && ++sp < PCAP);
            if (win == xcd + 1u) role = (int)rank;
        }
        s_role = role;
    }
    __syncthreads();
    const int b = s_role;
    if (b < 0) return;
    const int row0 = b * RPB;

    // ---- one-time: extract this block's sparse rows from dense W_res
    if (tid < RPB) cnt[tid] = 0;
    __syncthreads();
    for (int idx = tid; idx < RPB * R_N; idx += B2) {     // coalesced scan
        int r = idx >> 10, c = idx & (R_N - 1);
        float w = Wres[(size_t)(row0 + r) * R_N + c];
        if (w != 0.0f) {
            int slot = atomicAdd(&cnt[r], 1);
            if (slot < KMAX) ell[r][slot] = make_uint2((uint32_t)c, __float_as_uint(w));
        }
    }
    __syncthreads();

    // ---- counting-sort rows by nnz so each wave holds similar-degree rows
    if (tid <= KMAX) hist[tid] = 0;
    __syncthreads();
    if (tid < RPB) atomicAdd(&hist[min(cnt[tid], KMAX)], 1);
    __syncthreads();
    if (tid == 0) {
        int run = 0;
        for (int i = 0; i <= KMAX; ++i) { int c = hist[i]; hist[i] = run; run += c; }
    }
    __syncthreads();
    if (tid < RPB) {
        int c = min(cnt[tid], KMAX);
        int pos = atomicAdd(&hist[c], 1);
        rowmap[pos] = tid;
    }
    __syncthreads();

    // ---- hoist my slots into registers; wave-uniform compact bound kw;
    // per-lane bank-sort (static selection sort, NO dynamic reg indexing)
    const int rloc = rowmap[tid >> 3];    // permuted local row 0..127
    const int j    = tid & 7;             // 0..7
    const int row  = row0 + rloc;
    int   cols[NSL];
    float vals[NSL];
    int   kw;
    {
        int myn = cnt[rloc];
        if (myn > KMAX) myn = KMAX;
        int kcnt = (myn > j) ? (((myn - 1 - j) >> 3) + 1) : 0;
        int key[NSL];
#pragma unroll
        for (int k = 0; k < NSL; ++k) {
            int slot = j + k * TPR;
            if (slot < myn) {
                uint2 e = ell[rloc][slot];
                cols[k] = (int)e.x;
                vals[k] = __uint_as_float(e.y);
                key[k]  = (cols[k] - tid) & 31;          // bank offset from lane
            } else {
                cols[k] = tid & (R_N - 1);               // distinct pad col:
                vals[k] = 0.0f;                          // bank = tid%32, free
                key[k]  = 32 + k;                        // sorts to the tail
            }
        }
        // static selection sort: round-k banks ~ tid + k*delta (spread)
#pragma unroll
        for (int a = 0; a < NSL - 1; ++a)
#pragma unroll
            for (int c2 = a + 1; c2 < NSL; ++c2) {
                bool sw = key[c2] < key[a];
                int   tk = key[a];  key[a]  = sw ? key[c2]  : key[a];  key[c2]  = sw ? tk : key[c2];
                int   tc = cols[a]; cols[a] = sw ? cols[c2] : cols[a]; cols[c2] = sw ? tc : cols[c2];
                float tv = vals[a]; vals[a] = sw ? vals[c2] : vals[a]; vals[c2] = sw ? tv : vals[c2];
            }
        kw = kcnt;
#pragma unroll
        for (int off = 1; off < 64; off <<= 1) {
            int o = __shfl_xor(kw, off, 64);
            kw = (o > kw) ? o : kw;
        }
        kw = __builtin_amdgcn_readfirstlane(kw);   // wave-uniform gather depth
    }

    sbuf[1][tid] = state0[tid];                   // seed parity (t-1)&1 @ t=0
    float u_cur = (j == 0) ? out[row] : 0.0f;
    __syncthreads();

    const bool remote = (tid >> 7) != b;          // my slot is another block's
    uint32_t w_pre = 0;                           // pre-issued poll result

    // ---- scan: [wait pre-poll -> sbuf] -> barrier -> issue pre-poll(t+1)
    //            -> gather -> reduce -> publish
    for (int t = 0; t < T_N; ++t) {
        const int p = (t - 1) & 1;

        if (t > 0 && remote) {
            // value-tied wait: w_pre invalid until this asm (rule #18 guard)
            asm volatile("s_waitcnt vmcnt(0)" : "+v"(w_pre) :: "memory");
            __builtin_amdgcn_sched_barrier(0);
            const uint32_t want8 = (uint32_t)(t & 0xFF);  // s_{t-1} tag
            uint32_t w = w_pre;
            if ((w & 0xFFu) != want8) {           // stale pre-read: retry loop
                uint32_t* slot = slots + ((size_t)p << 10) + tid;
                int sp = 0;
                do { w = l2_atomic_read(slot);
                } while ((w & 0xFFu) != want8 && ++sp < PCAP);
            }
            sbuf[p][tid] = __uint_as_float(w & 0xFFFFFF00u);
        }

        float u_next = 0.0f;                      // issue AFTER the wait so
        if (j == 0 && t + 1 < T_N)                // its latency hides under
            u_next = out[(size_t)(t + 1) * R_N + row];  // gather+epilogue

        __syncthreads();                          // sbuf[p] complete

        if (remote && t + 1 < T_N)                // pre-poll t+1: flies during
            l2_atomic_read_issue(                 // gather; checked next iter
                slots + ((size_t)(t & 1) << 10) + tid, w_pre);

        const float* sb = sbuf[p];
        float acc = 0.0f;
#pragma unroll
        for (int k = 0; k < NSL; ++k) {
            if (k >= kw) break;                   // wave-uniform early exit
            acc = fmaf(vals[k], sb[cols[k]], acc);
        }

        acc += __shfl_xor(acc, 1, TPR);
        acc += __shfl_xor(acc, 2, TPR);
        acc += __shfl_xor(acc, 4, TPR);

        if (j == 0) {
            float y = fast_tanh(u_cur + acc);
            uint32_t bits = __float_as_uint(y);
            uint32_t pkt  = ((bits + 0x80u) & 0xFFFFFF00u)   // round to 24b
                          | ((uint32_t)(t + 1) & 0xFFu);
            // publish FIRST: consumer-visible latency off the critical path
            l2_store_u32(slots + ((size_t)(t & 1) << 10) + row, pkt);
            out[(size_t)t * R_N + row] = y;
            sbuf[t & 1][row] = y;                        // own-row fast path
        }
        u_cur = u_next;
        // sbuf[p] reuse safety: consumers read sbuf[p] in gather(t) before
        // their poll-write(t+2) which sits after barrier(t+1) -> safe with
        // one barrier/step. Tag aliasing (mod 256) needs 128-step skew;
        // actual skew <1 step by the data dependency.
    }
}

// ---------------------------------------------------------------- launcher
extern "C" void kernel_launch(void* const* d_in, const int* in_sizes, int n_in,
                              void* d_out, int out_size, void* d_ws, size_t ws_size,
                              hipStream_t stream)
{
    const float* X      = (const float*)d_in[0];   // (T, I)
    const float* W_in   = (const float*)d_in[1];   // (R, I)
    const float* W_res  = (const float*)d_in[2];   // (R, R)
    const float* state0 = (const float*)d_in[3];   // (R,)
    float* out = (float*)d_out;                    // (T, R)

    uint32_t* hdr   = (uint32_t*)d_ws;                     // 1 KB header
    uint32_t* slots = (uint32_t*)((char*)d_ws + 1024);     // 2 x 1024 x 4B

    // zero header + ring tags (harness poisons ws with 0xAA each launch)
    hipMemsetAsync(d_ws, 0, 1024 + (size_t)2 * R_N * sizeof(uint32_t), stream);

    dim3 g1(T_N / BT, R_N / BR);
    gemm_u_kernel<<<g1, 256, 0, stream>>>(X, W_in, out);

    esn_scan_kernel<<<NLAUNCH, B2, 0, stream>>>(W_res, state0, out, hdr, slots);
}

// Round 7
// 24148.065 us; speedup vs baseline: 1.0900x; 1.0900x over previous
//
#include <hip/hip_runtime.h>
#include <hip/hip_bf16.h>
#include <stdint.h>

// ESN: out[t] = tanh(U[t] + W_res @ s_{t-1}), T=16384 sequential steps.
// Kernel 1: U = X@W_in^T into d_out in place.
// Kernel 2: 8 worker blocks x 1024 threads claimed on ONE XCD via XCC_ID
// pigeonhole (proven). Transport v7 = R0's PROVEN direct per-slot tag poll
// (HW fact R4: only sc0 atomic RMWs observe remote plain stores on gfx950)
// with ONE change: 64-bit PAIR-SLOTS. Producer stores row r's 4B packet
// {24-bit rounded fp32 | 8-bit step tag} as the r-th dword (plain store,
// dirty line in the shared XCD L2). Consumers poll with global_atomic_add_x2
// (64-bit RMW add-0, sc0) reading TWO rows per op, check both tags, retry
// until both match, ds_write_b64 both values (2 lanes/bank = free).
// Own-block slots skipped (producers write sbuf directly, proven R5/R6).
// Rationale (R6 evidence): WRITE_SIZE tracks RMW count; R0's ~1800 cyc/step
// of XCD-L2 atomic-unit throughput (8192+ RMW/step) is the dominant term.
// Pair-slots halve base RMWs to 3584/step. Gather/barrier structure is
// R0-verbatim (bank-sort and pre-poll both measured-refuted in R5/R6).
// Mixed 4B-store / 8B-RMW safety: L2 serializes; a torn observation fails
// one tag and retries; RMW(+0) write-back cannot lose a store (L2 orders).

constexpr int T_N = 16384;
constexpr int R_N = 1024;
constexpr int I_N = 128;

// ---------------------------------------------------------------- kernel 1
constexpr int BT = 64, BR = 64;

__global__ __launch_bounds__(256) void gemm_u_kernel(
    const float* __restrict__ X, const float* __restrict__ Win,
    float* __restrict__ U)
{
    __shared__ float XS[BT][68];
    __shared__ float WS[BR][68];
    const int tid = threadIdx.x;
    const int ty = tid >> 4, tx = tid & 15;
    const int t0 = blockIdx.x * BT;
    const int r0 = blockIdx.y * BR;
    float acc[4][4] = {};

    for (int k0 = 0; k0 < I_N; k0 += 64) {
        for (int idx = tid; idx < BT * 16; idx += 256) {
            int row = idx >> 4, c4 = (idx & 15) << 2;
            *reinterpret_cast<float4*>(&XS[row][c4]) =
                *reinterpret_cast<const float4*>(&X[(size_t)(t0 + row) * I_N + k0 + c4]);
        }
        for (int idx = tid; idx < BR * 16; idx += 256) {
            int row = idx >> 4, c4 = (idx & 15) << 2;
            *reinterpret_cast<float4*>(&WS[row][c4]) =
                *reinterpret_cast<const float4*>(&Win[(size_t)(r0 + row) * I_N + k0 + c4]);
        }
        __syncthreads();
#pragma unroll
        for (int k = 0; k < 64; k += 4) {
            float4 a[4], b[4];
#pragma unroll
            for (int i = 0; i < 4; ++i)
                a[i] = *reinterpret_cast<const float4*>(&XS[ty + 16 * i][k]);
#pragma unroll
            for (int jj = 0; jj < 4; ++jj)
                b[jj] = *reinterpret_cast<const float4*>(&WS[tx + 16 * jj][k]);
#pragma unroll
            for (int i = 0; i < 4; ++i)
#pragma unroll
                for (int jj = 0; jj < 4; ++jj)
                    acc[i][jj] += a[i].x * b[jj].x + a[i].y * b[jj].y +
                                  a[i].z * b[jj].z + a[i].w * b[jj].w;
        }
        __syncthreads();
    }
#pragma unroll
    for (int i = 0; i < 4; ++i)
#pragma unroll
        for (int jj = 0; jj < 4; ++jj)
            U[(size_t)(t0 + ty + 16 * i) * R_N + (r0 + tx + 16 * jj)] = acc[i][jj];
}

// ---------------------------------------------------------------- kernel 2
constexpr int GBLK    = 8;             // worker blocks (one XCD)
constexpr int NLAUNCH = 64;            // pigeonhole: some XCD collects 8
constexpr int B2      = 1024;          // threads per block
constexpr int RPB     = R_N / GBLK;    // 128 rows per block
constexpr int TPR     = 8;             // threads per row
constexpr int KMAX    = 96;            // nnz/row cap (validated r1..r5)
constexpr int NSL     = KMAX / TPR;    // 12 register slots per thread
constexpr int NSLOT   = R_N / 2;       // 512 pair-slots per parity
constexpr int PCAP    = 1 << 20;       // anti-hang cap

__device__ __forceinline__ float fast_tanh(float x) {
    float ax = fabsf(x);
    float e  = __expf(-2.0f * ax);
    float y  = (1.0f - e) / (1.0f + e);
    return copysignf(y, x);
}

// SE-scope 64-bit atomic add 0 with return: executes at the XCD L2 -- the
// only load primitive proven coherent with remote plain stores (R0/R4).
// Reads TWO packed row packets per op.
__device__ __forceinline__ unsigned long long l2_atomic_read64(
    unsigned long long* addr)
{
    unsigned long long old;
    asm volatile("global_atomic_add_x2 %0, %1, %2, off sc0\n\t"
                 "s_waitcnt vmcnt(0)"
                 : "=v"(old) : "v"(addr), "v"(0ull) : "memory");
    return old;
}

// plain 4B store: dirty line in the shared XCD L2 (visible to sc0 RMWs)
__device__ __forceinline__ void l2_store_u32(uint32_t* addr, uint32_t v) {
    asm volatile("global_store_dword %0, %1, off"
                 :: "v"(addr), "v"(v) : "memory");
}

__global__ __launch_bounds__(1024) void esn_scan_kernel(
    const float* __restrict__ Wres, const float* __restrict__ state0,
    float* out, uint32_t* hdr, unsigned long long* slots)
{
    __shared__ int   s_role;
    __shared__ float sbuf[2][R_N];        // 8 KB ping-pong state
    __shared__ uint2 ell[RPB][KMAX];      // 96 KB (col, val-bits)
    __shared__ int   cnt[RPB];

    const int tid = threadIdx.x;

    // ---- claim: first XCD to collect 8 blocks wins (proven mechanism)
    if (tid == 0) {
        uint32_t xcd;
        asm volatile("s_getreg_b32 %0, hwreg(HW_REG_XCC_ID)" : "=s"(xcd));
        xcd &= 7u;
        uint32_t rank = __hip_atomic_fetch_add(&hdr[xcd], 1u,
                            __ATOMIC_RELAXED, __HIP_MEMORY_SCOPE_AGENT);
        int role = -1;
        if (rank < (uint32_t)GBLK) {
            if (rank == (uint32_t)(GBLK - 1)) {
                uint32_t expected = 0u;
                __hip_atomic_compare_exchange_strong(&hdr[8], &expected, xcd + 1u,
                    __ATOMIC_RELAXED, __ATOMIC_RELAXED, __HIP_MEMORY_SCOPE_AGENT);
            }
            uint32_t win = 0; int sp = 0;
            do {
                win = __hip_atomic_load(&hdr[8], __ATOMIC_RELAXED,
                                        __HIP_MEMORY_SCOPE_AGENT);
            } while (win == 0u && ++sp < PCAP);
            if (win == xcd + 1u) role = (int)rank;
        }
        s_role = role;
    }
    __syncthreads();
    const int b = s_role;
    if (b < 0) return;
    const int row0 = b * RPB;

    // ---- one-time: extract this block's sparse rows from dense W_res
    if (tid < RPB) cnt[tid] = 0;
    __syncthreads();
    for (int idx = tid; idx < RPB * R_N; idx += B2) {     // coalesced scan
        int r = idx >> 10, c = idx & (R_N - 1);
        float w = Wres[(size_t)(row0 + r) * R_N + c];
        if (w != 0.0f) {
            int slot = atomicAdd(&cnt[r], 1);
            if (slot < KMAX) ell[r][slot] = make_uint2((uint32_t)c, __float_as_uint(w));
        }
    }
    __syncthreads();

    // ---- hoist my slots into registers (R0-verbatim predicated layout)
    const int rloc = tid >> 3;            // local row 0..127
    const int j    = tid & 7;             // 0..7
    const int row  = row0 + rloc;
    int   cols[NSL];
    float vals[NSL];
    int   kcnt;
    {
        int myn = cnt[rloc];
        if (myn > KMAX) myn = KMAX;
        kcnt = (myn > j) ? (((myn - 1 - j) >> 3) + 1) : 0;
#pragma unroll
        for (int k = 0; k < NSL; ++k) {
            int slot = j + k * TPR;
            if (slot < myn) {
                uint2 e = ell[rloc][slot];
                cols[k] = (int)e.x;
                vals[k] = __uint_as_float(e.y);
            } else { cols[k] = 0; vals[k] = 0.0f; }
        }
    }

    sbuf[1][tid] = state0[tid];                   // seed parity (t-1)&1 @ t=0
    float u_cur = (j == 0) ? out[row] : 0.0f;
    __syncthreads();

    // pair-slot poller: tid<512 handles rows {2*tid, 2*tid+1}; skip own block
    const bool poller = (tid < NSLOT) && ((tid >> 6) != b);
    uint32_t* const slots4 = (uint32_t*)slots;    // dword view (producer side)

    // ---- sequential scan: poll -> sbuf -> ONE barrier -> gather -> publish
    for (int t = 0; t < T_N; ++t) {
        const int p = (t - 1) & 1;

        float u_next = 0.0f;
        if (j == 0 && t + 1 < T_N) u_next = out[(size_t)(t + 1) * R_N + row];

        if (t > 0 && poller) {
            unsigned long long* slot = slots + ((size_t)p << 9) + tid;
            const uint32_t want8 = (uint32_t)(t & 0xFF);  // s_{t-1} tag
            const unsigned long long want2 =
                (unsigned long long)want8 | ((unsigned long long)want8 << 32);
            const unsigned long long tmask = 0x000000FF000000FFull;
            unsigned long long w; int sp = 0;
            do { w = l2_atomic_read64(slot);      // 2 rows per RMW
            } while (((w ^ want2) & tmask) != 0ull && ++sp < PCAP);
            float2 st;
            st.x = __uint_as_float((uint32_t)w & 0xFFFFFF00u);
            st.y = __uint_as_float((uint32_t)(w >> 32) & 0xFFFFFF00u);
            *reinterpret_cast<float2*>(&sbuf[p][tid << 1]) = st;  // ds_write_b64
        }
        __syncthreads();                  // sbuf[p] complete

        const float* sb = sbuf[p];
        float acc = 0.0f;
#pragma unroll
        for (int k = 0; k < NSL; ++k)
            if (k < kcnt) acc = fmaf(vals[k], sb[cols[k]], acc);

        acc += __shfl_xor(acc, 1, TPR);
        acc += __shfl_xor(acc, 2, TPR);
        acc += __shfl_xor(acc, 4, TPR);

        if (j == 0) {
            float y = fast_tanh(u_cur + acc);
            uint32_t bits = __float_as_uint(y);
            uint32_t pkt  = ((bits + 0x80u) & 0xFFFFFF00u)   // round to 24b
                          | ((uint32_t)(t + 1) & 0xFFu);
            // publish FIRST: consumer-visible latency off the critical path
            l2_store_u32(slots4 + ((size_t)(t & 1) << 10) + row, pkt);
            out[(size_t)t * R_N + row] = y;
            sbuf[t & 1][row] = y;                        // own-row fast path
        }
        u_cur = u_next;
        // sbuf[p] reuse safety: consumers read sbuf[p] in gather(t) before
        // their poll-write(t+2) which sits after barrier(t+1) -> one
        // barrier/step suffices. Tag aliasing (mod 256) needs 128-step
        // producer/consumer skew; actual skew <2 steps by data dependency.
    }
}

// ---------------------------------------------------------------- launcher
extern "C" void kernel_launch(void* const* d_in, const int* in_sizes, int n_in,
                              void* d_out, int out_size, void* d_ws, size_t ws_size,
                              hipStream_t stream)
{
    const float* X      = (const float*)d_in[0];   // (T, I)
    const float* W_in   = (const float*)d_in[1];   // (R, I)
    const float* W_res  = (const float*)d_in[2];   // (R, R)
    const float* state0 = (const float*)d_in[3];   // (R,)
    float* out = (float*)d_out;                    // (T, R)

    uint32_t* hdr = (uint32_t*)d_ws;                          // 1 KB header
    unsigned long long* slots =
        (unsigned long long*)((char*)d_ws + 1024);            // 2 x 512 x 8B

    // zero header + ring slots (harness poisons ws with 0xAA each launch)
    hipMemsetAsync(d_ws, 0, 1024 + (size_t)2 * NSLOT * sizeof(unsigned long long),
                   stream);

    dim3 g1(T_N / BT, R_N / BR);
    gemm_u_kernel<<<g1, 256, 0, stream>>>(X, W_in, out);

    esn_scan_kernel<<<NLAUNCH, B2, 0, stream>>>(W_res, state0, out, hdr, slots);
}